// Round 11
// baseline (1445.057 us; speedup 1.0000x reference)
//
#include <hip/hip_runtime.h>

// GIN on MI355X. Round 11:
//  - y/u quarter-major (4 slabs of N x 16 bf16 = 3.2 MB each). Aggregation
//    runs as 4 SEQUENTIAL launches, one slab per launch: working set fits
//    every XCD's 4 MB L2 regardless of block->XCD mapping (R8's mistake was
//    interleaving quarters in one launch + relying on dispatch mapping).
//  - k_agg_q: wave per node, lanes = 4 k-offsets x 16 features -> each gather
//    instr = 4 neighbor sub-rows = 128 B; NT on slots/deg (streamed), normal
//    loads on y (reused). R10's mistake was NT on the reused side.
//  - build split back to standalone fill (no LDS, high occ) + standalone gemm.
//  - k_fused / k_last_pool: R8's quarter-major staging (validated correct).

constexpr int N   = 100000;
constexpr int E   = 1600000;
constexpr int DIN = 128;
constexpr int H   = 64;
constexpr int OUT = 16;
constexpr int G   = 512;
constexpr int SLOT = 64;

constexpr int NB_EDGES    = (E + 255) / 256;       // 6250
constexpr int NB_TILE64   = (N + 63) / 64;         // 1563
constexpr int NB_WAVENODE = (N * 64 + 255) / 256;  // 25000 (wave per node)

__device__ __forceinline__ float bf2f(unsigned short u) {
  union { unsigned int i; float f; } v;
  v.i = ((unsigned int)u) << 16;
  return v.f;
}
__device__ __forceinline__ unsigned int f2bf(float f) {
  union { float f; unsigned int i; } v;
  v.f = f;
  unsigned int r = v.i + 0x7fff + ((v.i >> 16) & 1);  // RNE
  return r >> 16;
}

// ---- slotted adjacency fill: 1 atomic + NT store per edge, no LDS ----
__global__ void k_fill_slots(const int* __restrict__ src, const int* __restrict__ dst,
                             int* __restrict__ deg, int* __restrict__ slots) {
  int e = blockIdx.x * 256 + threadIdx.x;
  if (e < E) {
    int s = src[e];
    int d = dst[e];
    int p = atomicAdd(&deg[d], 1);
    if (p < SLOT) __builtin_nontemporal_store(s, &slots[(size_t)d * SLOT + p]);
  }
}

// ---- y0 = x @ w1_0, quarter-major bf16 out. 64-node tile per block. ----
__global__ __launch_bounds__(256, 4) void k_gemm_in(const float* __restrict__ x,
                                                    const float* __restrict__ w1,
                                                    unsigned short* __restrict__ y) {
  __shared__ unsigned int sx[64 * 65];  // packed bf16 pairs, 16.6 KB
  int t = threadIdx.x;
  int nb = blockIdx.x * 64;
  int rows = min(64, N - nb);
#pragma unroll
  for (int it = 0; it < 8; ++it) {
    int idx4 = it * 256 + t;
    int r = idx4 >> 5, d4 = idx4 & 31;
    if (r < rows) {
      float4 v = ((const float4*)(x + (size_t)(nb + r) * DIN))[d4];
      sx[r * 65 + d4 * 2]     = f2bf(v.x) | (f2bf(v.y) << 16);
      sx[r * 65 + d4 * 2 + 1] = f2bf(v.z) | (f2bf(v.w) << 16);
    }
  }
  __syncthreads();
  int l = t & 63;
  int jg = __builtin_amdgcn_readfirstlane(t >> 6);
  float acc[16];
#pragma unroll
  for (int j = 0; j < 16; ++j) acc[j] = 0.f;
#pragma unroll 2
  for (int dd = 0; dd < 64; ++dd) {
    unsigned int pv = sx[l * 65 + dd];
    float vlo = bf2f((unsigned short)(pv & 0xffff));
    float vhi = bf2f((unsigned short)(pv >> 16));
    const float* wr0 = w1 + (2 * dd) * H + jg * 16;
    const float* wr1 = wr0 + H;
#pragma unroll
    for (int j = 0; j < 16; ++j) acc[j] += vlo * wr0[j] + vhi * wr1[j];
  }
  __syncthreads();
  unsigned int* so = sx;  // 64 rows x 32 uints, stride 33
#pragma unroll
  for (int k = 0; k < 8; ++k)
    so[l * 33 + jg * 8 + k] = f2bf(acc[2 * k]) | (f2bf(acc[2 * k + 1]) << 16);
  __syncthreads();
  unsigned int* yo = (unsigned int*)y;
#pragma unroll
  for (int it = 0; it < 8; ++it) {
    int m = it * 256 + t;  // 4 quarters x 64 rows x 8 uints
    int q = m >> 9, rem = m & 511;
    int r = rem >> 3, c = rem & 7;
    if (r < rows)
      yo[(size_t)q * (N * 8) + (size_t)(nb + r) * 8 + c] = so[r * 33 + q * 8 + c];
  }
}

// ---- one quarter of u = bf16(relu(y + A*y + b1)). Wave per node; lane =
//      (k4 = lane>>4, sub = lane&15). Gather instr covers 4 neighbor 32 B
//      sub-rows = 128 B. Slab (3.2 MB) is L2-resident during this launch. ----
__global__ void k_agg_q(const unsigned short* __restrict__ yq,
                        const int* __restrict__ deg,
                        const int* __restrict__ slots,
                        const float* __restrict__ b1q,
                        unsigned short* __restrict__ uq) {
  int w = (blockIdx.x * 256 + threadIdx.x) >> 6;
  int lane = threadIdx.x & 63;
  if (w >= N) return;
  int k4 = lane >> 4, sub = lane & 15;
  const int* srow = slots + (size_t)w * SLOT;
  int d = min(__builtin_nontemporal_load(&deg[w]), SLOT);
  float a = (k4 == 0) ? bf2f(yq[(size_t)w * 16 + sub]) : 0.f;
  // lane covers edges k4, k4+4, k4+8, ...; 4 edges/lane (16/wave) per iter
  int e0 = k4;
  for (; e0 + 12 < d; e0 += 16) {
    int c0 = __builtin_nontemporal_load(&srow[e0]);
    int c1 = __builtin_nontemporal_load(&srow[e0 + 4]);
    int c2 = __builtin_nontemporal_load(&srow[e0 + 8]);
    int c3 = __builtin_nontemporal_load(&srow[e0 + 12]);
    unsigned short g0 = yq[(size_t)c0 * 16 + sub];
    unsigned short g1 = yq[(size_t)c1 * 16 + sub];
    unsigned short g2 = yq[(size_t)c2 * 16 + sub];
    unsigned short g3 = yq[(size_t)c3 * 16 + sub];
    a += bf2f(g0) + bf2f(g1);
    a += bf2f(g2) + bf2f(g3);
  }
  for (; e0 < d; e0 += 4) {
    int c = __builtin_nontemporal_load(&srow[e0]);
    a += bf2f(yq[(size_t)c * 16 + sub]);
  }
  a += __shfl_xor(a, 16);
  a += __shfl_xor(a, 32);
  if (k4 == 0) {
    float r = fmaxf(a + b1q[sub], 0.f);
    uq[(size_t)w * 16 + sub] = (unsigned short)f2bf(r);
  }
}

// ---- y_next = (relu(u @ w2 + b2)) @ w1next; quarter-major bf16 in/out. ----
__global__ __launch_bounds__(256, 4) void k_fused(const unsigned short* __restrict__ u,
                                                  const float* __restrict__ w2,
                                                  const float* __restrict__ b2,
                                                  const float* __restrict__ w1n,
                                                  unsigned short* __restrict__ yout) {
  __shared__ unsigned int sau[64 * 34];  // 8.7 KB packed bf16
  __shared__ float sb[64 * 65];          // 16.6 KB
  int t = threadIdx.x;
  int nb = blockIdx.x * 64;
  int rows = min(64, N - nb);
  const unsigned int* u32 = (const unsigned int*)u;
#pragma unroll
  for (int it = 0; it < 8; ++it) {
    int m = it * 256 + t;
    int q = m >> 9, rem = m & 511;
    int r = rem >> 3, c = rem & 7;
    if (r < rows)
      sau[r * 34 + q * 8 + c] = u32[(size_t)q * (N * 8) + (size_t)(nb + r) * 8 + c];
  }
  __syncthreads();
  int l = t & 63;
  int jg = __builtin_amdgcn_readfirstlane(t >> 6);
  float h[16];
#pragma unroll
  for (int j = 0; j < 16; ++j) h[j] = b2[jg * 16 + j];
#pragma unroll 2
  for (int dd = 0; dd < 32; ++dd) {
    unsigned int pv = sau[l * 34 + dd];
    float vlo = bf2f((unsigned short)(pv & 0xffff));
    float vhi = bf2f((unsigned short)(pv >> 16));
    const float* wr0 = w2 + (2 * dd) * H + jg * 16;
    const float* wr1 = wr0 + H;
#pragma unroll
    for (int j = 0; j < 16; ++j) h[j] += vlo * wr0[j] + vhi * wr1[j];
  }
#pragma unroll
  for (int j = 0; j < 16; ++j) sb[l * 65 + jg * 16 + j] = fmaxf(h[j], 0.f);
  __syncthreads();
  float a[16];
#pragma unroll
  for (int j = 0; j < 16; ++j) a[j] = 0.f;
#pragma unroll 4
  for (int d = 0; d < H; ++d) {
    float v = sb[l * 65 + d];
    const float* wr = w1n + d * H + jg * 16;
#pragma unroll
    for (int j = 0; j < 16; ++j) a[j] += v * wr[j];
  }
  unsigned int* so = sau;  // dead after first barrier
#pragma unroll
  for (int k = 0; k < 8; ++k)
    so[l * 33 + jg * 8 + k] = f2bf(a[2 * k]) | (f2bf(a[2 * k + 1]) << 16);
  __syncthreads();
  unsigned int* yo = (unsigned int*)yout;
#pragma unroll
  for (int it = 0; it < 8; ++it) {
    int m = it * 256 + t;
    int q = m >> 9, rem = m & 511;
    int r = rem >> 3, c = rem & 7;
    if (r < rows)
      yo[(size_t)q * (N * 8) + (size_t)(nb + r) * 8 + c] = so[r * 33 + q * 8 + c];
  }
}

// ---- layer 4: h5 = relu(u @ w2 + b2) + segment-reduce pool into g[G][64] ----
__global__ __launch_bounds__(256, 4) void k_last_pool(const unsigned short* __restrict__ u,
                                                      const float* __restrict__ w2,
                                                      const float* __restrict__ b2,
                                                      const int* __restrict__ batch,
                                                      float* __restrict__ g) {
  __shared__ unsigned int sau[64 * 34];
  __shared__ float sb[64 * 65];
  __shared__ int sbatch[64];
  int t = threadIdx.x;
  int nb = blockIdx.x * 64;
  int rows = min(64, N - nb);
  const unsigned int* u32 = (const unsigned int*)u;
#pragma unroll
  for (int it = 0; it < 8; ++it) {
    int m = it * 256 + t;
    int q = m >> 9, rem = m & 511;
    int r = rem >> 3, c = rem & 7;
    if (r < rows)
      sau[r * 34 + q * 8 + c] = u32[(size_t)q * (N * 8) + (size_t)(nb + r) * 8 + c];
  }
  if (t < 64) sbatch[t] = batch[min(nb + t, N - 1)];
  __syncthreads();
  int l = t & 63;
  int jg = __builtin_amdgcn_readfirstlane(t >> 6);
  float h[16];
#pragma unroll
  for (int j = 0; j < 16; ++j) h[j] = b2[jg * 16 + j];
#pragma unroll 2
  for (int dd = 0; dd < 32; ++dd) {
    unsigned int pv = sau[l * 34 + dd];
    float vlo = bf2f((unsigned short)(pv & 0xffff));
    float vhi = bf2f((unsigned short)(pv >> 16));
    const float* wr0 = w2 + (2 * dd) * H + jg * 16;
    const float* wr1 = wr0 + H;
#pragma unroll
    for (int j = 0; j < 16; ++j) h[j] += vlo * wr0[j] + vhi * wr1[j];
  }
#pragma unroll
  for (int j = 0; j < 16; ++j) sb[l * 65 + jg * 16 + j] = fmaxf(h[j], 0.f);
  __syncthreads();
  int d = t & 63;
  int q = t >> 6;
  int r0 = q * 16;
  int bprev = sbatch[r0];
  float acc = 0.f;
#pragma unroll 4
  for (int r = 0; r < 16; ++r) {
    int row = r0 + r;
    if (row >= rows) break;
    int b = sbatch[row];
    if (b != bprev) {
      __hip_atomic_fetch_add(&g[(size_t)bprev * H + d], acc,
                             __ATOMIC_RELAXED, __HIP_MEMORY_SCOPE_AGENT);
      acc = 0.f;
      bprev = b;
    }
    acc += sb[row * 65 + d];
  }
  if (r0 < rows)
    __hip_atomic_fetch_add(&g[(size_t)bprev * H + d], acc,
                           __ATOMIC_RELAXED, __HIP_MEMORY_SCOPE_AGENT);
}

// out[n] = relu(g[n] @ mw1 + mb1) @ mw2 + mb2
__global__ void k_readout(const float* __restrict__ g, const float* __restrict__ mw1,
                          const float* __restrict__ mb1, const float* __restrict__ mw2,
                          const float* __restrict__ mb2, float* __restrict__ out) {
  int n = blockIdx.x * 64 + threadIdx.x;
  if (n >= G) return;
  float acc[H];
#pragma unroll
  for (int j = 0; j < H; ++j) acc[j] = mb1[j];
  const float* gr = g + (size_t)n * H;
  for (int d = 0; d < H; ++d) {
    float gd = gr[d];
    const float* wr = mw1 + d * H;
#pragma unroll
    for (int j = 0; j < H; ++j) acc[j] += gd * wr[j];
  }
#pragma unroll
  for (int j = 0; j < H; ++j) acc[j] = fmaxf(acc[j], 0.f);
  float o[OUT];
#pragma unroll
  for (int tt = 0; tt < OUT; ++tt) o[tt] = mb2[tt];
  for (int d = 0; d < H; ++d) {
    float hd = acc[d];
    const float* wr = mw2 + d * OUT;
#pragma unroll
    for (int tt = 0; tt < OUT; ++tt) o[tt] += hd * wr[tt];
  }
#pragma unroll
  for (int tt = 0; tt < OUT; ++tt) out[(size_t)n * OUT + tt] = o[tt];
}

extern "C" void kernel_launch(void* const* d_in, const int* in_sizes, int n_in,
                              void* d_out, int out_size, void* d_ws, size_t ws_size,
                              hipStream_t stream) {
  const float* x     = (const float*)d_in[0];
  const int*   ei    = (const int*)d_in[1];
  const int*   batch = (const int*)d_in[2];
  const float* w1_0  = (const float*)d_in[3];
  const float* b1_0  = (const float*)d_in[4];
  const float* w2_0  = (const float*)d_in[5];
  const float* b2_0  = (const float*)d_in[6];
  const float* w1_r  = (const float*)d_in[7];
  const float* b1_r  = (const float*)d_in[8];
  const float* w2_r  = (const float*)d_in[9];
  const float* b2_r  = (const float*)d_in[10];
  const float* mw1   = (const float*)d_in[11];
  const float* mb1   = (const float*)d_in[12];
  const float* mw2   = (const float*)d_in[13];
  const float* mb2   = (const float*)d_in[14];
  float* out = (float*)d_out;

  const int* src = ei;
  const int* dst = ei + E;

  char* ws = (char*)d_ws;
  size_t off = 0;
  auto alloc = [&](size_t bytes) -> void* {
    void* p = ws + off;
    off = (off + bytes + 255) & ~(size_t)255;
    return p;
  };
  unsigned short* ybuf = (unsigned short*)alloc((size_t)N * H * 2);  // quarter-major
  unsigned short* ubuf = (unsigned short*)alloc((size_t)N * H * 2);  // quarter-major
  int* deg    = (int*)alloc((size_t)N * 4);
  int* slots  = (int*)alloc((size_t)N * SLOT * 4);                   // 25.6 MB
  float* gbuf = (float*)alloc((size_t)G * H * 4);

  hipMemsetAsync(deg, 0, (size_t)N * 4, stream);
  hipMemsetAsync(gbuf, 0, (size_t)G * H * 4, stream);

  // ---- adjacency fill + input GEMM (separate: fill wants full occupancy) ----
  k_fill_slots<<<NB_EDGES, 256, 0, stream>>>(src, dst, deg, slots);
  k_gemm_in<<<NB_TILE64, 256, 0, stream>>>(x, w1_0, ybuf);

  // ---- layers 0..4: 4 sequential quarter-agg passes, then fused MLP ----
  const float* b1s[5] = {b1_0, b1_r, b1_r + H, b1_r + 2 * H, b1_r + 3 * H};
  for (int layer = 0; layer < 5; ++layer) {
    for (int q = 0; q < 4; ++q)
      k_agg_q<<<NB_WAVENODE, 256, 0, stream>>>(ybuf + (size_t)q * N * 16, deg, slots,
                                               b1s[layer] + q * 16,
                                               ubuf + (size_t)q * N * 16);
    if (layer == 0) {
      k_fused<<<NB_TILE64, 256, 0, stream>>>(ubuf, w2_0, b2_0, w1_r, ybuf);
    } else if (layer < 4) {
      int i = layer - 1;
      k_fused<<<NB_TILE64, 256, 0, stream>>>(ubuf, w2_r + i * H * H, b2_r + i * H,
                                             w1_r + (i + 1) * H * H, ybuf);
    } else {
      k_last_pool<<<NB_TILE64, 256, 0, stream>>>(ubuf, w2_r + 3 * H * H, b2_r + 3 * H,
                                                 batch, gbuf);
    }
  }

  // ---- readout ----
  k_readout<<<8, 64, 0, stream>>>(gbuf, mw1, mb1, mw2, mb2, out);
}

// Round 12
// 666.696 us; speedup vs baseline: 2.1675x; 2.1675x over previous
//
#include <hip/hip_runtime.h>

// GIN on MI355X. Round 12 = Round 9 (best known, 741 us) with one change:
//  - k_build_gemm block->role mapping INTERLEAVED (every 5th block = gemm
//    tile) so fill (atomic-latency-bound) and gemm (VALU-bound) are
//    co-resident on every CU for the whole kernel, instead of running as
//    two serial phases (R9 measured zero overlap: 186 us = 140 + 46).
//  - agg reverted to R9 exact form (R10's NT-on-reused-data and deeper
//    bursts regressed; R8/R11 locality restructurings regressed).

constexpr int N   = 100000;
constexpr int E   = 1600000;
constexpr int DIN = 128;
constexpr int H   = 64;
constexpr int OUT = 16;
constexpr int G   = 512;
constexpr int SLOT = 64;  // max degree capacity; P(Binom(1.6e6,1e-5) > 64) ~ 0

constexpr int NB_EDGES    = (E + 255) / 256;       // 6250
constexpr int NB_TILE64   = (N + 63) / 64;         // 1563
constexpr int NB_BUILD    = NB_TILE64 + NB_EDGES;  // 7813
constexpr int NB_WAVENODE = (N * 64 + 255) / 256;  // 25000 (wave per node)

__device__ __forceinline__ float bf2f(unsigned short u) {
  union { unsigned int i; float f; } v;
  v.i = ((unsigned int)u) << 16;
  return v.f;
}
__device__ __forceinline__ unsigned int f2bf(float f) {
  union { float f; unsigned int i; } v;
  v.f = f;
  unsigned int r = v.i + 0x7fff + ((v.i >> 16) & 1);  // RNE
  return r >> 16;
}

// ---- fused build: interleaved roles. blockIdx % 5 == 0 -> gemm tile
//      (tile = blockIdx/5, 1563 tiles); else -> fill block
//      (fill_idx = blockIdx - blockIdx/5 - 1, 6250 blocks). ----
__global__ __launch_bounds__(256, 4) void k_build_gemm(const int* __restrict__ src,
                                                       const int* __restrict__ dst,
                                                       int* __restrict__ deg,
                                                       int* __restrict__ slots,
                                                       const float* __restrict__ x,
                                                       const float* __restrict__ w1,
                                                       unsigned short* __restrict__ y) {
  __shared__ unsigned int sx[64 * 65];  // 16.6 KB (packed bf16 pairs)
  int t = threadIdx.x;
  int b = blockIdx.x;
  int q5 = b / 5;
  if (b - q5 * 5 != 0) {
    // ---- fill role ----
    int e = (b - q5 - 1) * 256 + t;
    if (e < E) {
      int s = src[e];
      int d = dst[e];
      int p = atomicAdd(&deg[d], 1);
      if (p < SLOT) __builtin_nontemporal_store(s, &slots[(size_t)d * SLOT + p]);
    }
    return;
  }
  // ---- gemm role ----
  int nb = q5 * 64;
  int rows = min(64, N - nb);
#pragma unroll
  for (int it = 0; it < 8; ++it) {
    int idx4 = it * 256 + t;  // float4 index, 0..2047
    int r = idx4 >> 5, d4 = idx4 & 31;
    if (r < rows) {
      float4 v = ((const float4*)(x + (size_t)(nb + r) * DIN))[d4];
      sx[r * 65 + d4 * 2]     = f2bf(v.x) | (f2bf(v.y) << 16);
      sx[r * 65 + d4 * 2 + 1] = f2bf(v.z) | (f2bf(v.w) << 16);
    }
  }
  __syncthreads();
  int l = t & 63;
  int jg = __builtin_amdgcn_readfirstlane(t >> 6);
  float acc[16];
#pragma unroll
  for (int j = 0; j < 16; ++j) acc[j] = 0.f;
#pragma unroll 2
  for (int dd = 0; dd < 64; ++dd) {
    unsigned int pv = sx[l * 65 + dd];
    float vlo = bf2f((unsigned short)(pv & 0xffff));
    float vhi = bf2f((unsigned short)(pv >> 16));
    const float* wr0 = w1 + (2 * dd) * H + jg * 16;
    const float* wr1 = wr0 + H;
#pragma unroll
    for (int j = 0; j < 16; ++j) acc[j] += vlo * wr0[j] + vhi * wr1[j];
  }
  __syncthreads();
  unsigned int* so = sx;  // reuse: 64 rows x 32 uints, stride 33 (2112 <= 4160)
#pragma unroll
  for (int k = 0; k < 8; ++k)
    so[l * 33 + jg * 8 + k] = f2bf(acc[2 * k]) | (f2bf(acc[2 * k + 1]) << 16);
  __syncthreads();
  unsigned int* yo = (unsigned int*)y;
#pragma unroll
  for (int it = 0; it < 8; ++it) {
    int m = it * 256 + t;
    int r = m >> 5, c = m & 31;
    if (r < rows) yo[(size_t)(nb + r) * 32 + c] = so[r * 33 + c];
  }
}

// ---- u = bf16(relu(y + A*y + b1)); wave/node, lane/feat, 8 outstanding. ----
__global__ void k_agg(const unsigned short* __restrict__ y, const int* __restrict__ deg,
                      const int* __restrict__ slots, const float* __restrict__ b1,
                      unsigned short* __restrict__ u) {
  int w = (blockIdx.x * 256 + threadIdx.x) >> 6;
  int lane = threadIdx.x & 63;
  if (w >= N) return;
  const int* srow = slots + (size_t)w * SLOT;
  int d = min(deg[w], SLOT);
  float a0 = bf2f(y[(size_t)w * H + lane]);
  float a1 = 0.f, a2 = 0.f, a3 = 0.f, a4 = 0.f, a5 = 0.f, a6 = 0.f, a7 = 0.f;
  int kend = d & ~7;
  for (int k = 0; k < kend; k += 8) {
    int c0 = srow[k],     c1 = srow[k + 1], c2 = srow[k + 2], c3 = srow[k + 3];
    int c4 = srow[k + 4], c5 = srow[k + 5], c6 = srow[k + 6], c7 = srow[k + 7];
    a0 += bf2f(y[(size_t)c0 * H + lane]);
    a1 += bf2f(y[(size_t)c1 * H + lane]);
    a2 += bf2f(y[(size_t)c2 * H + lane]);
    a3 += bf2f(y[(size_t)c3 * H + lane]);
    a4 += bf2f(y[(size_t)c4 * H + lane]);
    a5 += bf2f(y[(size_t)c5 * H + lane]);
    a6 += bf2f(y[(size_t)c6 * H + lane]);
    a7 += bf2f(y[(size_t)c7 * H + lane]);
  }
  int k = kend;
  if (d & 4) {
    int c0 = srow[k], c1 = srow[k + 1], c2 = srow[k + 2], c3 = srow[k + 3];
    a0 += bf2f(y[(size_t)c0 * H + lane]);
    a1 += bf2f(y[(size_t)c1 * H + lane]);
    a2 += bf2f(y[(size_t)c2 * H + lane]);
    a3 += bf2f(y[(size_t)c3 * H + lane]);
    k += 4;
  }
  if (d & 2) {
    int c0 = srow[k], c1 = srow[k + 1];
    a4 += bf2f(y[(size_t)c0 * H + lane]);
    a5 += bf2f(y[(size_t)c1 * H + lane]);
    k += 2;
  }
  if (d & 1) {
    int c0 = srow[k];
    a6 += bf2f(y[(size_t)c0 * H + lane]);
  }
  float r = ((a0 + a1) + (a2 + a3)) + ((a4 + a5) + (a6 + a7)) + b1[lane];
  u[(size_t)w * H + lane] = (unsigned short)f2bf(fmaxf(r, 0.f));
}

// ---- y = (relu(u @ w2 + b2)) @ w1next; u bf16 in, y bf16 out (row-major).
//      In-place y safe: never reads yout. ----
__global__ __launch_bounds__(256, 4) void k_fused(const unsigned short* __restrict__ u,
                                                  const float* __restrict__ w2,
                                                  const float* __restrict__ b2,
                                                  const float* __restrict__ w1n,
                                                  unsigned short* __restrict__ yout) {
  __shared__ unsigned int sau[64 * 33];  // 8.4 KB packed bf16
  __shared__ float sb[64 * 65];          // 16.6 KB
  int t = threadIdx.x;
  int nb = blockIdx.x * 64;
  int rows = min(64, N - nb);
  const unsigned int* u32 = (const unsigned int*)u;
#pragma unroll
  for (int it = 0; it < 8; ++it) {
    int m = it * 256 + t;
    int r = m >> 5, c = m & 31;
    if (r < rows) sau[r * 33 + c] = u32[(size_t)(nb + r) * 32 + c];
  }
  __syncthreads();
  int l = t & 63;
  int jg = __builtin_amdgcn_readfirstlane(t >> 6);
  float h[16];
#pragma unroll
  for (int j = 0; j < 16; ++j) h[j] = b2[jg * 16 + j];
#pragma unroll 2
  for (int dd = 0; dd < 32; ++dd) {
    unsigned int pv = sau[l * 33 + dd];
    float vlo = bf2f((unsigned short)(pv & 0xffff));
    float vhi = bf2f((unsigned short)(pv >> 16));
    const float* wr0 = w2 + (2 * dd) * H + jg * 16;
    const float* wr1 = wr0 + H;
#pragma unroll
    for (int j = 0; j < 16; ++j) h[j] += vlo * wr0[j] + vhi * wr1[j];
  }
#pragma unroll
  for (int j = 0; j < 16; ++j) sb[l * 65 + jg * 16 + j] = fmaxf(h[j], 0.f);
  __syncthreads();  // sau reads complete
  float a[16];
#pragma unroll
  for (int j = 0; j < 16; ++j) a[j] = 0.f;
#pragma unroll 4
  for (int d = 0; d < H; ++d) {
    float v = sb[l * 65 + d];
    const float* wr = w1n + d * H + jg * 16;
#pragma unroll
    for (int j = 0; j < 16; ++j) a[j] += v * wr[j];
  }
  unsigned int* so = sau;  // reuse
#pragma unroll
  for (int k = 0; k < 8; ++k)
    so[l * 33 + jg * 8 + k] = f2bf(a[2 * k]) | (f2bf(a[2 * k + 1]) << 16);
  __syncthreads();
  unsigned int* yo = (unsigned int*)yout;
#pragma unroll
  for (int it = 0; it < 8; ++it) {
    int m = it * 256 + t;
    int r = m >> 5, c = m & 31;
    if (r < rows) yo[(size_t)(nb + r) * 32 + c] = so[r * 33 + c];
  }
}

// ---- layer 4: h5 = relu(u @ w2 + b2) + segment-reduce pool into g[G][64] ----
__global__ __launch_bounds__(256, 4) void k_last_pool(const unsigned short* __restrict__ u,
                                                      const float* __restrict__ w2,
                                                      const float* __restrict__ b2,
                                                      const int* __restrict__ batch,
                                                      float* __restrict__ g) {
  __shared__ unsigned int sau[64 * 33];
  __shared__ float sb[64 * 65];
  __shared__ int sbatch[64];
  int t = threadIdx.x;
  int nb = blockIdx.x * 64;
  int rows = min(64, N - nb);
  const unsigned int* u32 = (const unsigned int*)u;
#pragma unroll
  for (int it = 0; it < 8; ++it) {
    int m = it * 256 + t;
    int r = m >> 5, c = m & 31;
    if (r < rows) sau[r * 33 + c] = u32[(size_t)(nb + r) * 32 + c];
  }
  if (t < 64) sbatch[t] = batch[min(nb + t, N - 1)];
  __syncthreads();
  int l = t & 63;
  int jg = __builtin_amdgcn_readfirstlane(t >> 6);
  float h[16];
#pragma unroll
  for (int j = 0; j < 16; ++j) h[j] = b2[jg * 16 + j];
#pragma unroll 2
  for (int dd = 0; dd < 32; ++dd) {
    unsigned int pv = sau[l * 33 + dd];
    float vlo = bf2f((unsigned short)(pv & 0xffff));
    float vhi = bf2f((unsigned short)(pv >> 16));
    const float* wr0 = w2 + (2 * dd) * H + jg * 16;
    const float* wr1 = wr0 + H;
#pragma unroll
    for (int j = 0; j < 16; ++j) h[j] += vlo * wr0[j] + vhi * wr1[j];
  }
#pragma unroll
  for (int j = 0; j < 16; ++j) sb[l * 65 + jg * 16 + j] = fmaxf(h[j], 0.f);
  __syncthreads();
  // segment-reduce 16 rows per thread along sorted batch; one atomic per run
  int d = t & 63;
  int q = t >> 6;
  int r0 = q * 16;
  int bprev = sbatch[r0];
  float acc = 0.f;
#pragma unroll 4
  for (int r = 0; r < 16; ++r) {
    int row = r0 + r;
    if (row >= rows) break;
    int b = sbatch[row];
    if (b != bprev) {
      __hip_atomic_fetch_add(&g[(size_t)bprev * H + d], acc,
                             __ATOMIC_RELAXED, __HIP_MEMORY_SCOPE_AGENT);
      acc = 0.f;
      bprev = b;
    }
    acc += sb[row * 65 + d];
  }
  if (r0 < rows)
    __hip_atomic_fetch_add(&g[(size_t)bprev * H + d], acc,
                           __ATOMIC_RELAXED, __HIP_MEMORY_SCOPE_AGENT);
}

// out[n] = relu(g[n] @ mw1 + mb1) @ mw2 + mb2
__global__ void k_readout(const float* __restrict__ g, const float* __restrict__ mw1,
                          const float* __restrict__ mb1, const float* __restrict__ mw2,
                          const float* __restrict__ mb2, float* __restrict__ out) {
  int n = blockIdx.x * 64 + threadIdx.x;
  if (n >= G) return;
  float acc[H];
#pragma unroll
  for (int j = 0; j < H; ++j) acc[j] = mb1[j];
  const float* gr = g + (size_t)n * H;
  for (int d = 0; d < H; ++d) {
    float gd = gr[d];
    const float* wr = mw1 + d * H;
#pragma unroll
    for (int j = 0; j < H; ++j) acc[j] += gd * wr[j];
  }
#pragma unroll
  for (int j = 0; j < H; ++j) acc[j] = fmaxf(acc[j], 0.f);
  float o[OUT];
#pragma unroll
  for (int tt = 0; tt < OUT; ++tt) o[tt] = mb2[tt];
  for (int d = 0; d < H; ++d) {
    float hd = acc[d];
    const float* wr = mw2 + d * OUT;
#pragma unroll
    for (int tt = 0; tt < OUT; ++tt) o[tt] += hd * wr[tt];
  }
#pragma unroll
  for (int tt = 0; tt < OUT; ++tt) out[(size_t)n * OUT + tt] = o[tt];
}

extern "C" void kernel_launch(void* const* d_in, const int* in_sizes, int n_in,
                              void* d_out, int out_size, void* d_ws, size_t ws_size,
                              hipStream_t stream) {
  const float* x     = (const float*)d_in[0];
  const int*   ei    = (const int*)d_in[1];
  const int*   batch = (const int*)d_in[2];
  const float* w1_0  = (const float*)d_in[3];
  const float* b1_0  = (const float*)d_in[4];
  const float* w2_0  = (const float*)d_in[5];
  const float* b2_0  = (const float*)d_in[6];
  const float* w1_r  = (const float*)d_in[7];
  const float* b1_r  = (const float*)d_in[8];
  const float* w2_r  = (const float*)d_in[9];
  const float* b2_r  = (const float*)d_in[10];
  const float* mw1   = (const float*)d_in[11];
  const float* mb1   = (const float*)d_in[12];
  const float* mw2   = (const float*)d_in[13];
  const float* mb2   = (const float*)d_in[14];
  float* out = (float*)d_out;

  const int* src = ei;
  const int* dst = ei + E;

  char* ws = (char*)d_ws;
  size_t off = 0;
  auto alloc = [&](size_t bytes) -> void* {
    void* p = ws + off;
    off = (off + bytes + 255) & ~(size_t)255;
    return p;
  };
  unsigned short* ybuf = (unsigned short*)alloc((size_t)N * H * 2);   // bf16
  unsigned short* ubuf = (unsigned short*)alloc((size_t)N * H * 2);   // bf16
  int* deg    = (int*)alloc((size_t)N * 4);
  int* slots  = (int*)alloc((size_t)N * SLOT * 4);                    // 25.6 MB
  float* gbuf = (float*)alloc((size_t)G * H * 4);

  hipMemsetAsync(deg, 0, (size_t)N * 4, stream);
  hipMemsetAsync(gbuf, 0, (size_t)G * H * 4, stream);

  // ---- single-pass adjacency build + input GEMM (interleaved roles) ----
  k_build_gemm<<<NB_BUILD, 256, 0, stream>>>(src, dst, deg, slots, x, w1_0, ybuf);

  // ---- layers 0..3: agg -> fused MLP ----
  k_agg<<<NB_WAVENODE, 256, 0, stream>>>(ybuf, deg, slots, b1_0, ubuf);
  k_fused<<<NB_TILE64, 256, 0, stream>>>(ubuf, w2_0, b2_0, w1_r, ybuf);
  for (int i = 0; i < 3; ++i) {
    k_agg<<<NB_WAVENODE, 256, 0, stream>>>(ybuf, deg, slots, b1_r + i * H, ubuf);
    k_fused<<<NB_TILE64, 256, 0, stream>>>(ubuf, w2_r + i * H * H, b2_r + i * H,
                                           w1_r + (i + 1) * H * H, ybuf);
  }

  // ---- layer 4: agg, then GEMM2 + pool ----
  k_agg<<<NB_WAVENODE, 256, 0, stream>>>(ybuf, deg, slots, b1_r + 3 * H, ubuf);
  k_last_pool<<<NB_TILE64, 256, 0, stream>>>(ubuf, w2_r + 3 * H * H, b2_r + 3 * H,
                                             batch, gbuf);

  // ---- readout ----
  k_readout<<<8, 64, 0, stream>>>(gbuf, mw1, mb1, mw2, mb2, out);
}

// Round 13
// 612.225 us; speedup vs baseline: 2.3603x; 1.0890x over previous
//
#include <hip/hip_runtime.h>

// GIN on MI355X. Round 13 = Round 12 + MFMA MLP:
//  - k_prep: 9 weight matrices (w2_0, w2_r[0..3], w1_r[0..3]) pre-transposed
//    to bf16 [n][k] once per launch (B-fragments become contiguous 16B loads).
//  - k_fused / k_last_pool: 64x64x64 GEMMs via mfma_f32_16x16x32_bf16.
//    Wave = 16-node m-tile; 4 n-tiles x 2 k-steps; A-frags from 144B-stride
//    LDS rows (ds_read_b128); GEMM1->GEMM2 via LDS, same-wave rows (no barrier).
//  - build (interleaved roles) and agg unchanged from R12 (both at their walls).

constexpr int N   = 100000;
constexpr int E   = 1600000;
constexpr int DIN = 128;
constexpr int H   = 64;
constexpr int OUT = 16;
constexpr int G   = 512;
constexpr int SLOT = 64;

constexpr int NB_EDGES    = (E + 255) / 256;       // 6250
constexpr int NB_TILE64   = (N + 63) / 64;         // 1563
constexpr int NB_BUILD    = NB_TILE64 + NB_EDGES;  // 7813
constexpr int NB_WAVENODE = (N * 64 + 255) / 256;  // 25000

typedef __attribute__((ext_vector_type(8))) short bf16x8;
typedef __attribute__((ext_vector_type(4))) float f32x4;

__device__ __forceinline__ float bf2f(unsigned short u) {
  union { unsigned int i; float f; } v;
  v.i = ((unsigned int)u) << 16;
  return v.f;
}
__device__ __forceinline__ unsigned int f2bf(float f) {
  union { float f; unsigned int i; } v;
  v.f = f;
  unsigned int r = v.i + 0x7fff + ((v.i >> 16) & 1);  // RNE
  return r >> 16;
}

// ---- weight prep: wt[mat][n*64+k] = bf16(w[mat][k*64+n]), 9 mats 64x64.
//      mats: 0=w2_0, 1..4=w2_r[0..3], 5..8=w1_r[0..3] ----
__global__ void k_prep(const float* __restrict__ w2_0, const float* __restrict__ w2_r,
                       const float* __restrict__ w1_r, unsigned short* __restrict__ wt) {
  int i = blockIdx.x * 256 + threadIdx.x;
  if (i >= 9 * 4096) return;
  int mat = i >> 12, rem = i & 4095;
  int n = rem >> 6, k = rem & 63;
  const float* s;
  if (mat == 0) s = w2_0;
  else if (mat < 5) s = w2_r + (mat - 1) * 4096;
  else s = w1_r + (mat - 5) * 4096;
  wt[i] = (unsigned short)f2bf(s[k * 64 + n]);
}

// ---- fused build: interleaved roles (R12). blockIdx%5==0 -> gemm tile. ----
__global__ __launch_bounds__(256, 4) void k_build_gemm(const int* __restrict__ src,
                                                       const int* __restrict__ dst,
                                                       int* __restrict__ deg,
                                                       int* __restrict__ slots,
                                                       const float* __restrict__ x,
                                                       const float* __restrict__ w1,
                                                       unsigned short* __restrict__ y) {
  __shared__ unsigned int sx[64 * 65];
  int t = threadIdx.x;
  int b = blockIdx.x;
  int q5 = b / 5;
  if (b - q5 * 5 != 0) {
    int e = (b - q5 - 1) * 256 + t;
    if (e < E) {
      int s = src[e];
      int d = dst[e];
      int p = atomicAdd(&deg[d], 1);
      if (p < SLOT) __builtin_nontemporal_store(s, &slots[(size_t)d * SLOT + p]);
    }
    return;
  }
  int nb = q5 * 64;
  int rows = min(64, N - nb);
#pragma unroll
  for (int it = 0; it < 8; ++it) {
    int idx4 = it * 256 + t;
    int r = idx4 >> 5, d4 = idx4 & 31;
    if (r < rows) {
      float4 v = ((const float4*)(x + (size_t)(nb + r) * DIN))[d4];
      sx[r * 65 + d4 * 2]     = f2bf(v.x) | (f2bf(v.y) << 16);
      sx[r * 65 + d4 * 2 + 1] = f2bf(v.z) | (f2bf(v.w) << 16);
    }
  }
  __syncthreads();
  int l = t & 63;
  int jg = __builtin_amdgcn_readfirstlane(t >> 6);
  float acc[16];
#pragma unroll
  for (int j = 0; j < 16; ++j) acc[j] = 0.f;
#pragma unroll 2
  for (int dd = 0; dd < 64; ++dd) {
    unsigned int pv = sx[l * 65 + dd];
    float vlo = bf2f((unsigned short)(pv & 0xffff));
    float vhi = bf2f((unsigned short)(pv >> 16));
    const float* wr0 = w1 + (2 * dd) * H + jg * 16;
    const float* wr1 = wr0 + H;
#pragma unroll
    for (int j = 0; j < 16; ++j) acc[j] += vlo * wr0[j] + vhi * wr1[j];
  }
  __syncthreads();
  unsigned int* so = sx;
#pragma unroll
  for (int k = 0; k < 8; ++k)
    so[l * 33 + jg * 8 + k] = f2bf(acc[2 * k]) | (f2bf(acc[2 * k + 1]) << 16);
  __syncthreads();
  unsigned int* yo = (unsigned int*)y;
#pragma unroll
  for (int it = 0; it < 8; ++it) {
    int m = it * 256 + t;
    int r = m >> 5, c = m & 31;
    if (r < rows) yo[(size_t)(nb + r) * 32 + c] = so[r * 33 + c];
  }
}

// ---- u = bf16(relu(y + A*y + b1)); wave/node, 8 outstanding (R9 form). ----
__global__ void k_agg(const unsigned short* __restrict__ y, const int* __restrict__ deg,
                      const int* __restrict__ slots, const float* __restrict__ b1,
                      unsigned short* __restrict__ u) {
  int w = (blockIdx.x * 256 + threadIdx.x) >> 6;
  int lane = threadIdx.x & 63;
  if (w >= N) return;
  const int* srow = slots + (size_t)w * SLOT;
  int d = min(deg[w], SLOT);
  float a0 = bf2f(y[(size_t)w * H + lane]);
  float a1 = 0.f, a2 = 0.f, a3 = 0.f, a4 = 0.f, a5 = 0.f, a6 = 0.f, a7 = 0.f;
  int kend = d & ~7;
  for (int k = 0; k < kend; k += 8) {
    int c0 = srow[k],     c1 = srow[k + 1], c2 = srow[k + 2], c3 = srow[k + 3];
    int c4 = srow[k + 4], c5 = srow[k + 5], c6 = srow[k + 6], c7 = srow[k + 7];
    a0 += bf2f(y[(size_t)c0 * H + lane]);
    a1 += bf2f(y[(size_t)c1 * H + lane]);
    a2 += bf2f(y[(size_t)c2 * H + lane]);
    a3 += bf2f(y[(size_t)c3 * H + lane]);
    a4 += bf2f(y[(size_t)c4 * H + lane]);
    a5 += bf2f(y[(size_t)c5 * H + lane]);
    a6 += bf2f(y[(size_t)c6 * H + lane]);
    a7 += bf2f(y[(size_t)c7 * H + lane]);
  }
  int k = kend;
  if (d & 4) {
    int c0 = srow[k], c1 = srow[k + 1], c2 = srow[k + 2], c3 = srow[k + 3];
    a0 += bf2f(y[(size_t)c0 * H + lane]);
    a1 += bf2f(y[(size_t)c1 * H + lane]);
    a2 += bf2f(y[(size_t)c2 * H + lane]);
    a3 += bf2f(y[(size_t)c3 * H + lane]);
    k += 4;
  }
  if (d & 2) {
    int c0 = srow[k], c1 = srow[k + 1];
    a4 += bf2f(y[(size_t)c0 * H + lane]);
    a5 += bf2f(y[(size_t)c1 * H + lane]);
    k += 2;
  }
  if (d & 1) {
    int c0 = srow[k];
    a6 += bf2f(y[(size_t)c0 * H + lane]);
  }
  float r = ((a0 + a1) + (a2 + a3)) + ((a4 + a5) + (a6 + a7)) + b1[lane];
  u[(size_t)w * H + lane] = (unsigned short)f2bf(fmaxf(r, 0.f));
}

// ---- MFMA fused: Y = (relu(U @ W2 + b2)) @ W1n. u/y bf16 row-major.
//      w2t/w1t: bf16 [n][k]. Wave = 16-node m-tile. ----
__global__ __launch_bounds__(256, 4) void k_fused(const unsigned int* __restrict__ u32,
                                                  const unsigned short* __restrict__ w2t,
                                                  const float* __restrict__ b2,
                                                  const unsigned short* __restrict__ w1t,
                                                  unsigned short* __restrict__ yout) {
  __shared__ unsigned short sU[64 * 72];  // 9.2 KB, row stride 144 B (16B-aligned)
  __shared__ unsigned short sH[64 * 72];  // 9.2 KB
  int t = threadIdx.x;
  int nb = blockIdx.x * 64;
  int rows = min(64, N - nb);
  unsigned int* sU32 = (unsigned int*)sU;
#pragma unroll
  for (int it = 0; it < 8; ++it) {
    int m = it * 256 + t;
    int r = m >> 5, c = m & 31;
    if (r < rows) sU32[r * 36 + c] = u32[(size_t)(nb + r) * 32 + c];
  }
  __syncthreads();
  int lane = t & 63;
  int w = __builtin_amdgcn_readfirstlane(t >> 6);
  int sub = lane & 15, quad = lane >> 4;
  // GEMM1: H = relu(U @ W2 + b2)
  f32x4 acc[4];
#pragma unroll
  for (int nt = 0; nt < 4; ++nt) {
    float bv = b2[nt * 16 + sub];
    acc[nt].x = bv; acc[nt].y = bv; acc[nt].z = bv; acc[nt].w = bv;
  }
#pragma unroll
  for (int ks = 0; ks < 2; ++ks) {
    bf16x8 a = *(const bf16x8*)&sU[(w * 16 + sub) * 72 + ks * 32 + quad * 8];
#pragma unroll
    for (int nt = 0; nt < 4; ++nt) {
      bf16x8 bb = *(const bf16x8*)&w2t[(nt * 16 + sub) * 64 + ks * 32 + quad * 8];
      acc[nt] = __builtin_amdgcn_mfma_f32_16x16x32_bf16(a, bb, acc[nt], 0, 0, 0);
    }
  }
  // H (bf16) to LDS: C/D layout row = quad*4+reg, col = nt*16+sub (own rows)
#pragma unroll
  for (int nt = 0; nt < 4; ++nt) {
    sH[(w * 16 + quad * 4 + 0) * 72 + nt * 16 + sub] = (unsigned short)f2bf(fmaxf(acc[nt].x, 0.f));
    sH[(w * 16 + quad * 4 + 1) * 72 + nt * 16 + sub] = (unsigned short)f2bf(fmaxf(acc[nt].y, 0.f));
    sH[(w * 16 + quad * 4 + 2) * 72 + nt * 16 + sub] = (unsigned short)f2bf(fmaxf(acc[nt].z, 0.f));
    sH[(w * 16 + quad * 4 + 3) * 72 + nt * 16 + sub] = (unsigned short)f2bf(fmaxf(acc[nt].w, 0.f));
  }
  // GEMM2: Y = H @ W1n — same-wave rows, no barrier needed
  f32x4 acc2[4];
#pragma unroll
  for (int nt = 0; nt < 4; ++nt) { acc2[nt].x = 0.f; acc2[nt].y = 0.f; acc2[nt].z = 0.f; acc2[nt].w = 0.f; }
#pragma unroll
  for (int ks = 0; ks < 2; ++ks) {
    bf16x8 a = *(const bf16x8*)&sH[(w * 16 + sub) * 72 + ks * 32 + quad * 8];
#pragma unroll
    for (int nt = 0; nt < 4; ++nt) {
      bf16x8 bb = *(const bf16x8*)&w1t[(nt * 16 + sub) * 64 + ks * 32 + quad * 8];
      acc2[nt] = __builtin_amdgcn_mfma_f32_16x16x32_bf16(a, bb, acc2[nt], 0, 0, 0);
    }
  }
  // Y bf16 into sU region (own rows; this wave's GEMM1 reads are done)
#pragma unroll
  for (int nt = 0; nt < 4; ++nt) {
    sU[(w * 16 + quad * 4 + 0) * 72 + nt * 16 + sub] = (unsigned short)f2bf(acc2[nt].x);
    sU[(w * 16 + quad * 4 + 1) * 72 + nt * 16 + sub] = (unsigned short)f2bf(acc2[nt].y);
    sU[(w * 16 + quad * 4 + 2) * 72 + nt * 16 + sub] = (unsigned short)f2bf(acc2[nt].z);
    sU[(w * 16 + quad * 4 + 3) * 72 + nt * 16 + sub] = (unsigned short)f2bf(acc2[nt].w);
  }
  __syncthreads();
  unsigned int* yo = (unsigned int*)yout;
#pragma unroll
  for (int it = 0; it < 8; ++it) {
    int m = it * 256 + t;
    int r = m >> 5, c = m & 31;
    if (r < rows) yo[(size_t)(nb + r) * 32 + c] = sU32[r * 36 + c];
  }
}

// ---- layer 4: H5 = relu(U @ W2 + b2) via MFMA + segment-reduce pool ----
__global__ __launch_bounds__(256, 4) void k_last_pool(const unsigned int* __restrict__ u32,
                                                      const unsigned short* __restrict__ w2t,
                                                      const float* __restrict__ b2,
                                                      const int* __restrict__ batch,
                                                      float* __restrict__ g) {
  __shared__ unsigned short sU[64 * 72];  // 9.2 KB
  __shared__ float sb[64 * 65];           // 16.6 KB
  __shared__ int sbatch[64];
  int t = threadIdx.x;
  int nb = blockIdx.x * 64;
  int rows = min(64, N - nb);
  unsigned int* sU32 = (unsigned int*)sU;
#pragma unroll
  for (int it = 0; it < 8; ++it) {
    int m = it * 256 + t;
    int r = m >> 5, c = m & 31;
    if (r < rows) sU32[r * 36 + c] = u32[(size_t)(nb + r) * 32 + c];
  }
  if (t < 64) sbatch[t] = batch[min(nb + t, N - 1)];
  __syncthreads();
  int lane = t & 63;
  int w = __builtin_amdgcn_readfirstlane(t >> 6);
  int sub = lane & 15, quad = lane >> 4;
  f32x4 acc[4];
#pragma unroll
  for (int nt = 0; nt < 4; ++nt) {
    float bv = b2[nt * 16 + sub];
    acc[nt].x = bv; acc[nt].y = bv; acc[nt].z = bv; acc[nt].w = bv;
  }
#pragma unroll
  for (int ks = 0; ks < 2; ++ks) {
    bf16x8 a = *(const bf16x8*)&sU[(w * 16 + sub) * 72 + ks * 32 + quad * 8];
#pragma unroll
    for (int nt = 0; nt < 4; ++nt) {
      bf16x8 bb = *(const bf16x8*)&w2t[(nt * 16 + sub) * 64 + ks * 32 + quad * 8];
      acc[nt] = __builtin_amdgcn_mfma_f32_16x16x32_bf16(a, bb, acc[nt], 0, 0, 0);
    }
  }
#pragma unroll
  for (int nt = 0; nt < 4; ++nt) {
    sb[(w * 16 + quad * 4 + 0) * 65 + nt * 16 + sub] = fmaxf(acc[nt].x, 0.f);
    sb[(w * 16 + quad * 4 + 1) * 65 + nt * 16 + sub] = fmaxf(acc[nt].y, 0.f);
    sb[(w * 16 + quad * 4 + 2) * 65 + nt * 16 + sub] = fmaxf(acc[nt].z, 0.f);
    sb[(w * 16 + quad * 4 + 3) * 65 + nt * 16 + sub] = fmaxf(acc[nt].w, 0.f);
  }
  __syncthreads();
  // segment-reduce 16 rows per thread along sorted batch; one atomic per run
  int d = t & 63;
  int q = t >> 6;
  int r0 = q * 16;
  int bprev = sbatch[r0];
  float acc1 = 0.f;
#pragma unroll 4
  for (int r = 0; r < 16; ++r) {
    int row = r0 + r;
    if (row >= rows) break;
    int b = sbatch[row];
    if (b != bprev) {
      __hip_atomic_fetch_add(&g[(size_t)bprev * H + d], acc1,
                             __ATOMIC_RELAXED, __HIP_MEMORY_SCOPE_AGENT);
      acc1 = 0.f;
      bprev = b;
    }
    acc1 += sb[row * 65 + d];
  }
  if (r0 < rows)
    __hip_atomic_fetch_add(&g[(size_t)bprev * H + d], acc1,
                           __ATOMIC_RELAXED, __HIP_MEMORY_SCOPE_AGENT);
}

// out[n] = relu(g[n] @ mw1 + mb1) @ mw2 + mb2
__global__ void k_readout(const float* __restrict__ g, const float* __restrict__ mw1,
                          const float* __restrict__ mb1, const float* __restrict__ mw2,
                          const float* __restrict__ mb2, float* __restrict__ out) {
  int n = blockIdx.x * 64 + threadIdx.x;
  if (n >= G) return;
  float acc[H];
#pragma unroll
  for (int j = 0; j < H; ++j) acc[j] = mb1[j];
  const float* gr = g + (size_t)n * H;
  for (int d = 0; d < H; ++d) {
    float gd = gr[d];
    const float* wr = mw1 + d * H;
#pragma unroll
    for (int j = 0; j < H; ++j) acc[j] += gd * wr[j];
  }
#pragma unroll
  for (int j = 0; j < H; ++j) acc[j] = fmaxf(acc[j], 0.f);
  float o[OUT];
#pragma unroll
  for (int tt = 0; tt < OUT; ++tt) o[tt] = mb2[tt];
  for (int d = 0; d < H; ++d) {
    float hd = acc[d];
    const float* wr = mw2 + d * OUT;
#pragma unroll
    for (int tt = 0; tt < OUT; ++tt) o[tt] += hd * wr[tt];
  }
#pragma unroll
  for (int tt = 0; tt < OUT; ++tt) out[(size_t)n * OUT + tt] = o[tt];
}

extern "C" void kernel_launch(void* const* d_in, const int* in_sizes, int n_in,
                              void* d_out, int out_size, void* d_ws, size_t ws_size,
                              hipStream_t stream) {
  const float* x     = (const float*)d_in[0];
  const int*   ei    = (const int*)d_in[1];
  const int*   batch = (const int*)d_in[2];
  const float* w1_0  = (const float*)d_in[3];
  const float* b1_0  = (const float*)d_in[4];
  const float* w2_0  = (const float*)d_in[5];
  const float* b2_0  = (const float*)d_in[6];
  const float* w1_r  = (const float*)d_in[7];
  const float* b1_r  = (const float*)d_in[8];
  const float* w2_r  = (const float*)d_in[9];
  const float* b2_r  = (const float*)d_in[10];
  const float* mw1   = (const float*)d_in[11];
  const float* mb1   = (const float*)d_in[12];
  const float* mw2   = (const float*)d_in[13];
  const float* mb2   = (const float*)d_in[14];
  float* out = (float*)d_out;

  const int* src = ei;
  const int* dst = ei + E;

  char* ws = (char*)d_ws;
  size_t off = 0;
  auto alloc = [&](size_t bytes) -> void* {
    void* p = ws + off;
    off = (off + bytes + 255) & ~(size_t)255;
    return p;
  };
  unsigned short* ybuf = (unsigned short*)alloc((size_t)N * H * 2);   // bf16
  unsigned short* ubuf = (unsigned short*)alloc((size_t)N * H * 2);   // bf16
  int* deg    = (int*)alloc((size_t)N * 4);
  int* slots  = (int*)alloc((size_t)N * SLOT * 4);                    // 25.6 MB
  float* gbuf = (float*)alloc((size_t)G * H * 4);
  unsigned short* wt = (unsigned short*)alloc((size_t)9 * 4096 * 2);  // bf16 [n][k]

  hipMemsetAsync(deg, 0, (size_t)N * 4, stream);
  hipMemsetAsync(gbuf, 0, (size_t)G * H * 4, stream);

  // ---- weight prep + build (interleaved fill/gemm roles) ----
  k_prep<<<144, 256, 0, stream>>>(w2_0, w2_r, w1_r, wt);
  k_build_gemm<<<NB_BUILD, 256, 0, stream>>>(src, dst, deg, slots, x, w1_0, ybuf);

  // wt mats: 0=w2_0, 1..4=w2_r[0..3], 5..8=w1_r[0..3]
  unsigned short* w2t0 = wt;
  unsigned short* w2tr = wt + 4096;
  unsigned short* w1tr = wt + 5 * 4096;

  // ---- layers 0..3: agg -> MFMA fused MLP ----
  k_agg<<<NB_WAVENODE, 256, 0, stream>>>(ybuf, deg, slots, b1_0, ubuf);
  k_fused<<<NB_TILE64, 256, 0, stream>>>((const unsigned int*)ubuf, w2t0, b2_0,
                                         w1tr, ybuf);
  for (int i = 0; i < 3; ++i) {
    k_agg<<<NB_WAVENODE, 256, 0, stream>>>(ybuf, deg, slots, b1_r + i * H, ubuf);
    k_fused<<<NB_TILE64, 256, 0, stream>>>((const unsigned int*)ubuf,
                                           w2tr + i * 4096, b2_r + i * H,
                                           w1tr + (i + 1) * 4096, ybuf);
  }

  // ---- layer 4: agg, then MFMA GEMM2 + pool ----
  k_agg<<<NB_WAVENODE, 256, 0, stream>>>(ybuf, deg, slots, b1_r + 3 * H, ubuf);
  k_last_pool<<<NB_TILE64, 256, 0, stream>>>((const unsigned int*)ubuf,
                                             w2tr + 3 * 4096, b2_r + 3 * H,
                                             batch, gbuf);

  // ---- readout ----
  k_readout<<<8, 64, 0, stream>>>(gbuf, mw1, mb1, mw2, mb2, out);
}

// Round 14
// 591.149 us; speedup vs baseline: 2.4445x; 1.0357x over previous
//
#include <hip/hip_runtime.h>

// GIN on MI355X. Round 14 = Round 13 with one change (clean MLP-depth test):
//  - k_agg: wave split into two 32-lane halves; each lane loads a uint
//    (2 features); half 0 gathers even-position neighbors, half 1 odd.
//    One vmem instruction now fetches 2 rows (2 lines) -> 16 lines in
//    flight per wave (vs 8). Cross-half combine via 2x shfl_xor(32).
//    No NT on y (R10's confound removed). Line traffic unchanged.
//  - build / MFMA MLPs / pool / readout byte-identical to R13.

constexpr int N   = 100000;
constexpr int E   = 1600000;
constexpr int DIN = 128;
constexpr int H   = 64;
constexpr int OUT = 16;
constexpr int G   = 512;
constexpr int SLOT = 64;

constexpr int NB_EDGES    = (E + 255) / 256;       // 6250
constexpr int NB_TILE64   = (N + 63) / 64;         // 1563
constexpr int NB_BUILD    = NB_TILE64 + NB_EDGES;  // 7813
constexpr int NB_WAVENODE = (N * 64 + 255) / 256;  // 25000

typedef __attribute__((ext_vector_type(8))) short bf16x8;
typedef __attribute__((ext_vector_type(4))) float f32x4;

__device__ __forceinline__ float bf2f(unsigned short u) {
  union { unsigned int i; float f; } v;
  v.i = ((unsigned int)u) << 16;
  return v.f;
}
__device__ __forceinline__ unsigned int f2bf(float f) {
  union { float f; unsigned int i; } v;
  v.f = f;
  unsigned int r = v.i + 0x7fff + ((v.i >> 16) & 1);  // RNE
  return r >> 16;
}

// ---- weight prep: wt[mat][n*64+k] = bf16(w[mat][k*64+n]), 9 mats 64x64. ----
__global__ void k_prep(const float* __restrict__ w2_0, const float* __restrict__ w2_r,
                       const float* __restrict__ w1_r, unsigned short* __restrict__ wt) {
  int i = blockIdx.x * 256 + threadIdx.x;
  if (i >= 9 * 4096) return;
  int mat = i >> 12, rem = i & 4095;
  int n = rem >> 6, k = rem & 63;
  const float* s;
  if (mat == 0) s = w2_0;
  else if (mat < 5) s = w2_r + (mat - 1) * 4096;
  else s = w1_r + (mat - 5) * 4096;
  wt[i] = (unsigned short)f2bf(s[k * 64 + n]);
}

// ---- fused build: interleaved roles. blockIdx%5==0 -> gemm tile. ----
__global__ __launch_bounds__(256, 4) void k_build_gemm(const int* __restrict__ src,
                                                       const int* __restrict__ dst,
                                                       int* __restrict__ deg,
                                                       int* __restrict__ slots,
                                                       const float* __restrict__ x,
                                                       const float* __restrict__ w1,
                                                       unsigned short* __restrict__ y) {
  __shared__ unsigned int sx[64 * 65];
  int t = threadIdx.x;
  int b = blockIdx.x;
  int q5 = b / 5;
  if (b - q5 * 5 != 0) {
    int e = (b - q5 - 1) * 256 + t;
    if (e < E) {
      int s = src[e];
      int d = dst[e];
      int p = atomicAdd(&deg[d], 1);
      if (p < SLOT) __builtin_nontemporal_store(s, &slots[(size_t)d * SLOT + p]);
    }
    return;
  }
  int nb = q5 * 64;
  int rows = min(64, N - nb);
#pragma unroll
  for (int it = 0; it < 8; ++it) {
    int idx4 = it * 256 + t;
    int r = idx4 >> 5, d4 = idx4 & 31;
    if (r < rows) {
      float4 v = ((const float4*)(x + (size_t)(nb + r) * DIN))[d4];
      sx[r * 65 + d4 * 2]     = f2bf(v.x) | (f2bf(v.y) << 16);
      sx[r * 65 + d4 * 2 + 1] = f2bf(v.z) | (f2bf(v.w) << 16);
    }
  }
  __syncthreads();
  int l = t & 63;
  int jg = __builtin_amdgcn_readfirstlane(t >> 6);
  float acc[16];
#pragma unroll
  for (int j = 0; j < 16; ++j) acc[j] = 0.f;
#pragma unroll 2
  for (int dd = 0; dd < 64; ++dd) {
    unsigned int pv = sx[l * 65 + dd];
    float vlo = bf2f((unsigned short)(pv & 0xffff));
    float vhi = bf2f((unsigned short)(pv >> 16));
    const float* wr0 = w1 + (2 * dd) * H + jg * 16;
    const float* wr1 = wr0 + H;
#pragma unroll
    for (int j = 0; j < 16; ++j) acc[j] += vlo * wr0[j] + vhi * wr1[j];
  }
  __syncthreads();
  unsigned int* so = sx;
#pragma unroll
  for (int k = 0; k < 8; ++k)
    so[l * 33 + jg * 8 + k] = f2bf(acc[2 * k]) | (f2bf(acc[2 * k + 1]) << 16);
  __syncthreads();
  unsigned int* yo = (unsigned int*)y;
#pragma unroll
  for (int it = 0; it < 8; ++it) {
    int m = it * 256 + t;
    int r = m >> 5, c = m & 31;
    if (r < rows) yo[(size_t)(nb + r) * 32 + c] = so[r * 33 + c];
  }
}

// ---- u = bf16(relu(y + A*y + b1)); wave/node; dual-row gathers:
//      half = lane>>5 (even/odd neighbor stream), fl = lane&31 (2 features).
//      8 vmem instrs in flight x 2 rows each = 16 lines in flight. ----
__global__ void k_agg(const unsigned short* __restrict__ y, const int* __restrict__ deg,
                      const int* __restrict__ slots, const float* __restrict__ b1,
                      unsigned short* __restrict__ u) {
  int w = (blockIdx.x * 256 + threadIdx.x) >> 6;
  int lane = threadIdx.x & 63;
  if (w >= N) return;
  int half = lane >> 5, fl = lane & 31;
  const unsigned int* y32 = (const unsigned int*)y;
  const int* srow = slots + (size_t)w * SLOT;
  int d = min(deg[w], SLOT);
  int dp = d >> 1;  // neighbor pairs; position 2i+half belongs to this half
  float ax0 = 0.f, ay0 = 0.f, ax1 = 0.f, ay1 = 0.f;
  float ax2 = 0.f, ay2 = 0.f, ax3 = 0.f, ay3 = 0.f;
  float ax4 = 0.f, ay4 = 0.f, ax5 = 0.f, ay5 = 0.f;
  float ax6 = 0.f, ay6 = 0.f, ax7 = 0.f, ay7 = 0.f;
  // self row (add once: half 0 only)
  unsigned int sv = y32[(size_t)w * 32 + fl];
  if (half == 0) {
    ax0 += bf2f((unsigned short)(sv & 0xffff));
    ay0 += bf2f((unsigned short)(sv >> 16));
  }
  int i = 0;
  for (; i + 8 <= dp; i += 8) {
    int c0 = srow[2 * (i + 0) + half], c1 = srow[2 * (i + 1) + half];
    int c2 = srow[2 * (i + 2) + half], c3 = srow[2 * (i + 3) + half];
    int c4 = srow[2 * (i + 4) + half], c5 = srow[2 * (i + 5) + half];
    int c6 = srow[2 * (i + 6) + half], c7 = srow[2 * (i + 7) + half];
    unsigned int g0 = y32[(size_t)c0 * 32 + fl];
    unsigned int g1 = y32[(size_t)c1 * 32 + fl];
    unsigned int g2 = y32[(size_t)c2 * 32 + fl];
    unsigned int g3 = y32[(size_t)c3 * 32 + fl];
    unsigned int g4 = y32[(size_t)c4 * 32 + fl];
    unsigned int g5 = y32[(size_t)c5 * 32 + fl];
    unsigned int g6 = y32[(size_t)c6 * 32 + fl];
    unsigned int g7 = y32[(size_t)c7 * 32 + fl];
    ax0 += bf2f((unsigned short)(g0 & 0xffff)); ay0 += bf2f((unsigned short)(g0 >> 16));
    ax1 += bf2f((unsigned short)(g1 & 0xffff)); ay1 += bf2f((unsigned short)(g1 >> 16));
    ax2 += bf2f((unsigned short)(g2 & 0xffff)); ay2 += bf2f((unsigned short)(g2 >> 16));
    ax3 += bf2f((unsigned short)(g3 & 0xffff)); ay3 += bf2f((unsigned short)(g3 >> 16));
    ax4 += bf2f((unsigned short)(g4 & 0xffff)); ay4 += bf2f((unsigned short)(g4 >> 16));
    ax5 += bf2f((unsigned short)(g5 & 0xffff)); ay5 += bf2f((unsigned short)(g5 >> 16));
    ax6 += bf2f((unsigned short)(g6 & 0xffff)); ay6 += bf2f((unsigned short)(g6 >> 16));
    ax7 += bf2f((unsigned short)(g7 & 0xffff)); ay7 += bf2f((unsigned short)(g7 >> 16));
  }
  if (dp & 4) {
    int c0 = srow[2 * (i + 0) + half], c1 = srow[2 * (i + 1) + half];
    int c2 = srow[2 * (i + 2) + half], c3 = srow[2 * (i + 3) + half];
    unsigned int g0 = y32[(size_t)c0 * 32 + fl];
    unsigned int g1 = y32[(size_t)c1 * 32 + fl];
    unsigned int g2 = y32[(size_t)c2 * 32 + fl];
    unsigned int g3 = y32[(size_t)c3 * 32 + fl];
    ax0 += bf2f((unsigned short)(g0 & 0xffff)); ay0 += bf2f((unsigned short)(g0 >> 16));
    ax1 += bf2f((unsigned short)(g1 & 0xffff)); ay1 += bf2f((unsigned short)(g1 >> 16));
    ax2 += bf2f((unsigned short)(g2 & 0xffff)); ay2 += bf2f((unsigned short)(g2 >> 16));
    ax3 += bf2f((unsigned short)(g3 & 0xffff)); ay3 += bf2f((unsigned short)(g3 >> 16));
    i += 4;
  }
  if (dp & 2) {
    int c0 = srow[2 * (i + 0) + half], c1 = srow[2 * (i + 1) + half];
    unsigned int g0 = y32[(size_t)c0 * 32 + fl];
    unsigned int g1 = y32[(size_t)c1 * 32 + fl];
    ax4 += bf2f((unsigned short)(g0 & 0xffff)); ay4 += bf2f((unsigned short)(g0 >> 16));
    ax5 += bf2f((unsigned short)(g1 & 0xffff)); ay5 += bf2f((unsigned short)(g1 >> 16));
    i += 2;
  }
  if (dp & 1) {
    int c0 = srow[2 * i + half];
    unsigned int g0 = y32[(size_t)c0 * 32 + fl];
    ax6 += bf2f((unsigned short)(g0 & 0xffff)); ay6 += bf2f((unsigned short)(g0 >> 16));
  }
  if (d & 1) {  // last odd neighbor: half 0 only
    int c0 = srow[d - 1];
    if (half == 0) {
      unsigned int g0 = y32[(size_t)c0 * 32 + fl];
      ax7 += bf2f((unsigned short)(g0 & 0xffff)); ay7 += bf2f((unsigned short)(g0 >> 16));
    }
  }
  float sxv = ((ax0 + ax1) + (ax2 + ax3)) + ((ax4 + ax5) + (ax6 + ax7));
  float syv = ((ay0 + ay1) + (ay2 + ay3)) + ((ay4 + ay5) + (ay6 + ay7));
  sxv += __shfl_xor(sxv, 32);
  syv += __shfl_xor(syv, 32);
  if (half == 0) {
    float rx = fmaxf(sxv + b1[2 * fl], 0.f);
    float ry = fmaxf(syv + b1[2 * fl + 1], 0.f);
    ((unsigned int*)u)[(size_t)w * 32 + fl] = f2bf(rx) | (f2bf(ry) << 16);
  }
}

// ---- MFMA fused: Y = (relu(U @ W2 + b2)) @ W1n. ----
__global__ __launch_bounds__(256, 4) void k_fused(const unsigned int* __restrict__ u32,
                                                  const unsigned short* __restrict__ w2t,
                                                  const float* __restrict__ b2,
                                                  const unsigned short* __restrict__ w1t,
                                                  unsigned short* __restrict__ yout) {
  __shared__ unsigned short sU[64 * 72];
  __shared__ unsigned short sH[64 * 72];
  int t = threadIdx.x;
  int nb = blockIdx.x * 64;
  int rows = min(64, N - nb);
  unsigned int* sU32 = (unsigned int*)sU;
#pragma unroll
  for (int it = 0; it < 8; ++it) {
    int m = it * 256 + t;
    int r = m >> 5, c = m & 31;
    if (r < rows) sU32[r * 36 + c] = u32[(size_t)(nb + r) * 32 + c];
  }
  __syncthreads();
  int lane = t & 63;
  int w = __builtin_amdgcn_readfirstlane(t >> 6);
  int sub = lane & 15, quad = lane >> 4;
  f32x4 acc[4];
#pragma unroll
  for (int nt = 0; nt < 4; ++nt) {
    float bv = b2[nt * 16 + sub];
    acc[nt].x = bv; acc[nt].y = bv; acc[nt].z = bv; acc[nt].w = bv;
  }
#pragma unroll
  for (int ks = 0; ks < 2; ++ks) {
    bf16x8 a = *(const bf16x8*)&sU[(w * 16 + sub) * 72 + ks * 32 + quad * 8];
#pragma unroll
    for (int nt = 0; nt < 4; ++nt) {
      bf16x8 bb = *(const bf16x8*)&w2t[(nt * 16 + sub) * 64 + ks * 32 + quad * 8];
      acc[nt] = __builtin_amdgcn_mfma_f32_16x16x32_bf16(a, bb, acc[nt], 0, 0, 0);
    }
  }
#pragma unroll
  for (int nt = 0; nt < 4; ++nt) {
    sH[(w * 16 + quad * 4 + 0) * 72 + nt * 16 + sub] = (unsigned short)f2bf(fmaxf(acc[nt].x, 0.f));
    sH[(w * 16 + quad * 4 + 1) * 72 + nt * 16 + sub] = (unsigned short)f2bf(fmaxf(acc[nt].y, 0.f));
    sH[(w * 16 + quad * 4 + 2) * 72 + nt * 16 + sub] = (unsigned short)f2bf(fmaxf(acc[nt].z, 0.f));
    sH[(w * 16 + quad * 4 + 3) * 72 + nt * 16 + sub] = (unsigned short)f2bf(fmaxf(acc[nt].w, 0.f));
  }
  f32x4 acc2[4];
#pragma unroll
  for (int nt = 0; nt < 4; ++nt) { acc2[nt].x = 0.f; acc2[nt].y = 0.f; acc2[nt].z = 0.f; acc2[nt].w = 0.f; }
#pragma unroll
  for (int ks = 0; ks < 2; ++ks) {
    bf16x8 a = *(const bf16x8*)&sH[(w * 16 + sub) * 72 + ks * 32 + quad * 8];
#pragma unroll
    for (int nt = 0; nt < 4; ++nt) {
      bf16x8 bb = *(const bf16x8*)&w1t[(nt * 16 + sub) * 64 + ks * 32 + quad * 8];
      acc2[nt] = __builtin_amdgcn_mfma_f32_16x16x32_bf16(a, bb, acc2[nt], 0, 0, 0);
    }
  }
#pragma unroll
  for (int nt = 0; nt < 4; ++nt) {
    sU[(w * 16 + quad * 4 + 0) * 72 + nt * 16 + sub] = (unsigned short)f2bf(acc2[nt].x);
    sU[(w * 16 + quad * 4 + 1) * 72 + nt * 16 + sub] = (unsigned short)f2bf(acc2[nt].y);
    sU[(w * 16 + quad * 4 + 2) * 72 + nt * 16 + sub] = (unsigned short)f2bf(acc2[nt].z);
    sU[(w * 16 + quad * 4 + 3) * 72 + nt * 16 + sub] = (unsigned short)f2bf(acc2[nt].w);
  }
  __syncthreads();
  unsigned int* yo = (unsigned int*)yout;
#pragma unroll
  for (int it = 0; it < 8; ++it) {
    int m = it * 256 + t;
    int r = m >> 5, c = m & 31;
    if (r < rows) yo[(size_t)(nb + r) * 32 + c] = sU32[r * 36 + c];
  }
}

// ---- layer 4: H5 = relu(U @ W2 + b2) via MFMA + segment-reduce pool ----
__global__ __launch_bounds__(256, 4) void k_last_pool(const unsigned int* __restrict__ u32,
                                                      const unsigned short* __restrict__ w2t,
                                                      const float* __restrict__ b2,
                                                      const int* __restrict__ batch,
                                                      float* __restrict__ g) {
  __shared__ unsigned short sU[64 * 72];
  __shared__ float sb[64 * 65];
  __shared__ int sbatch[64];
  int t = threadIdx.x;
  int nb = blockIdx.x * 64;
  int rows = min(64, N - nb);
  unsigned int* sU32 = (unsigned int*)sU;
#pragma unroll
  for (int it = 0; it < 8; ++it) {
    int m = it * 256 + t;
    int r = m >> 5, c = m & 31;
    if (r < rows) sU32[r * 36 + c] = u32[(size_t)(nb + r) * 32 + c];
  }
  if (t < 64) sbatch[t] = batch[min(nb + t, N - 1)];
  __syncthreads();
  int lane = t & 63;
  int w = __builtin_amdgcn_readfirstlane(t >> 6);
  int sub = lane & 15, quad = lane >> 4;
  f32x4 acc[4];
#pragma unroll
  for (int nt = 0; nt < 4; ++nt) {
    float bv = b2[nt * 16 + sub];
    acc[nt].x = bv; acc[nt].y = bv; acc[nt].z = bv; acc[nt].w = bv;
  }
#pragma unroll
  for (int ks = 0; ks < 2; ++ks) {
    bf16x8 a = *(const bf16x8*)&sU[(w * 16 + sub) * 72 + ks * 32 + quad * 8];
#pragma unroll
    for (int nt = 0; nt < 4; ++nt) {
      bf16x8 bb = *(const bf16x8*)&w2t[(nt * 16 + sub) * 64 + ks * 32 + quad * 8];
      acc[nt] = __builtin_amdgcn_mfma_f32_16x16x32_bf16(a, bb, acc[nt], 0, 0, 0);
    }
  }
#pragma unroll
  for (int nt = 0; nt < 4; ++nt) {
    sb[(w * 16 + quad * 4 + 0) * 65 + nt * 16 + sub] = fmaxf(acc[nt].x, 0.f);
    sb[(w * 16 + quad * 4 + 1) * 65 + nt * 16 + sub] = fmaxf(acc[nt].y, 0.f);
    sb[(w * 16 + quad * 4 + 2) * 65 + nt * 16 + sub] = fmaxf(acc[nt].z, 0.f);
    sb[(w * 16 + quad * 4 + 3) * 65 + nt * 16 + sub] = fmaxf(acc[nt].w, 0.f);
  }
  __syncthreads();
  int d = t & 63;
  int q = t >> 6;
  int r0 = q * 16;
  int bprev = sbatch[r0];
  float acc1 = 0.f;
#pragma unroll 4
  for (int r = 0; r < 16; ++r) {
    int row = r0 + r;
    if (row >= rows) break;
    int b = sbatch[row];
    if (b != bprev) {
      __hip_atomic_fetch_add(&g[(size_t)bprev * H + d], acc1,
                             __ATOMIC_RELAXED, __HIP_MEMORY_SCOPE_AGENT);
      acc1 = 0.f;
      bprev = b;
    }
    acc1 += sb[row * 65 + d];
  }
  if (r0 < rows)
    __hip_atomic_fetch_add(&g[(size_t)bprev * H + d], acc1,
                           __ATOMIC_RELAXED, __HIP_MEMORY_SCOPE_AGENT);
}

// out[n] = relu(g[n] @ mw1 + mb1) @ mw2 + mb2
__global__ void k_readout(const float* __restrict__ g, const float* __restrict__ mw1,
                          const float* __restrict__ mb1, const float* __restrict__ mw2,
                          const float* __restrict__ mb2, float* __restrict__ out) {
  int n = blockIdx.x * 64 + threadIdx.x;
  if (n >= G) return;
  float acc[H];
#pragma unroll
  for (int j = 0; j < H; ++j) acc[j] = mb1[j];
  const float* gr = g + (size_t)n * H;
  for (int d = 0; d < H; ++d) {
    float gd = gr[d];
    const float* wr = mw1 + d * H;
#pragma unroll
    for (int j = 0; j < H; ++j) acc[j] += gd * wr[j];
  }
#pragma unroll
  for (int j = 0; j < H; ++j) acc[j] = fmaxf(acc[j], 0.f);
  float o[OUT];
#pragma unroll
  for (int tt = 0; tt < OUT; ++tt) o[tt] = mb2[tt];
  for (int d = 0; d < H; ++d) {
    float hd = acc[d];
    const float* wr = mw2 + d * OUT;
#pragma unroll
    for (int tt = 0; tt < OUT; ++tt) o[tt] += hd * wr[tt];
  }
#pragma unroll
  for (int tt = 0; tt < OUT; ++tt) out[(size_t)n * OUT + tt] = o[tt];
}

extern "C" void kernel_launch(void* const* d_in, const int* in_sizes, int n_in,
                              void* d_out, int out_size, void* d_ws, size_t ws_size,
                              hipStream_t stream) {
  const float* x     = (const float*)d_in[0];
  const int*   ei    = (const int*)d_in[1];
  const int*   batch = (const int*)d_in[2];
  const float* w1_0  = (const float*)d_in[3];
  const float* b1_0  = (const float*)d_in[4];
  const float* w2_0  = (const float*)d_in[5];
  const float* b2_0  = (const float*)d_in[6];
  const float* w1_r  = (const float*)d_in[7];
  const float* b1_r  = (const float*)d_in[8];
  const float* w2_r  = (const float*)d_in[9];
  const float* b2_r  = (const float*)d_in[10];
  const float* mw1   = (const float*)d_in[11];
  const float* mb1   = (const float*)d_in[12];
  const float* mw2   = (const float*)d_in[13];
  const float* mb2   = (const float*)d_in[14];
  float* out = (float*)d_out;

  const int* src = ei;
  const int* dst = ei + E;

  char* ws = (char*)d_ws;
  size_t off = 0;
  auto alloc = [&](size_t bytes) -> void* {
    void* p = ws + off;
    off = (off + bytes + 255) & ~(size_t)255;
    return p;
  };
  unsigned short* ybuf = (unsigned short*)alloc((size_t)N * H * 2);
  unsigned short* ubuf = (unsigned short*)alloc((size_t)N * H * 2);
  int* deg    = (int*)alloc((size_t)N * 4);
  int* slots  = (int*)alloc((size_t)N * SLOT * 4);
  float* gbuf = (float*)alloc((size_t)G * H * 4);
  unsigned short* wt = (unsigned short*)alloc((size_t)9 * 4096 * 2);

  hipMemsetAsync(deg, 0, (size_t)N * 4, stream);
  hipMemsetAsync(gbuf, 0, (size_t)G * H * 4, stream);

  k_prep<<<144, 256, 0, stream>>>(w2_0, w2_r, w1_r, wt);
  k_build_gemm<<<NB_BUILD, 256, 0, stream>>>(src, dst, deg, slots, x, w1_0, ybuf);

  unsigned short* w2t0 = wt;
  unsigned short* w2tr = wt + 4096;
  unsigned short* w1tr = wt + 5 * 4096;

  k_agg<<<NB_WAVENODE, 256, 0, stream>>>(ybuf, deg, slots, b1_0, ubuf);
  k_fused<<<NB_TILE64, 256, 0, stream>>>((const unsigned int*)ubuf, w2t0, b2_0,
                                         w1tr, ybuf);
  for (int i = 0; i < 3; ++i) {
    k_agg<<<NB_WAVENODE, 256, 0, stream>>>(ybuf, deg, slots, b1_r + i * H, ubuf);
    k_fused<<<NB_TILE64, 256, 0, stream>>>((const unsigned int*)ubuf,
                                           w2tr + i * 4096, b2_r + i * H,
                                           w1tr + (i + 1) * 4096, ybuf);
  }

  k_agg<<<NB_WAVENODE, 256, 0, stream>>>(ybuf, deg, slots, b1_r + 3 * H, ubuf);
  k_last_pool<<<NB_TILE64, 256, 0, stream>>>((const unsigned int*)ubuf,
                                             w2tr + 3 * 4096, b2_r + 3 * H,
                                             batch, gbuf);

  k_readout<<<8, 64, 0, stream>>>(gbuf, mw1, mb1, mw2, mb2, out);
}